// Round 10
// baseline (180.598 us; speedup 1.0000x reference)
//
#include <hip/hip_runtime.h>

typedef unsigned short ushort_t;
typedef __attribute__((ext_vector_type(8))) short bf16x8;
typedef __attribute__((ext_vector_type(4))) float f32x4;

#define NROWS 4096
#define DIM   256
#define NT    32                    // 128-row tiles
#define NBLK  (NT * (NT + 1) / 2)   // 528 triangular tiles
#define MARGINF 0.3f
#define READYF 0x1337C0DEu          // != 0xAAAAAAAA poison, != 0

// ---- order-preserving float<->uint encoding for atomic max/min ----
__device__ __forceinline__ unsigned enc_f(float f) {
  unsigned u = __float_as_uint(f);
  return (u & 0x80000000u) ? ~u : (u | 0x80000000u);
}
__device__ __forceinline__ float dec_f(unsigned k) {
  unsigned u = (k & 0x80000000u) ? (k ^ 0x80000000u) : ~k;
  return __uint_as_float(u);
}

__device__ __forceinline__ ushort_t f2b(float f) {  // fp32 -> bf16 bits, RNE
  unsigned u = __float_as_uint(f);
  u += 0x7fffu + ((u >> 16) & 1u);
  return (ushort_t)(u >> 16);
}

__device__ __forceinline__ void gload_lds16(const void* g, void* l) {
  __builtin_amdgcn_global_load_lds(
      (const __attribute__((address_space(1))) void*)g,
      (__attribute__((address_space(3))) void*)l, 16, 0, 0);
}

// ONE kernel: diagonal blocks prep (convert+norm+init) their tile and publish
// a flag; off-diagonal blocks wait on their two tiles' flags; everyone then
// runs the Gram+mining path; the last block to finish computes the mean loss.
// __launch_bounds__(256,3): 768 resident slots >= 528 blocks -> all blocks
// co-resident -> flag spin is deadlock-free (LDS 38KB*3=114<=160KB).
__global__ __launch_bounds__(256, 3) void k_all(
    const float* __restrict__ F, const int* __restrict__ lab,
    ushort_t* __restrict__ Fb, float* __restrict__ nrm,
    unsigned* __restrict__ posk, unsigned* __restrict__ negk,
    unsigned* __restrict__ flags, unsigned* __restrict__ ctr,
    float* __restrict__ out) {
  __shared__ alignas(16) ushort_t As[2][128 * 32];   // [row][k] linear, 8KB each
  __shared__ alignas(16) ushort_t Bs[2][128 * 32];
  __shared__ int labi[128], labj[128];
  __shared__ float nrmi[128], nrmj[128];
  __shared__ float redp[2][128], redn[2][128];       // row-side, by wn
  __shared__ float redpc[2][128], rednc[2][128];     // col-side, by wm
  __shared__ int is_last;

  const int tid = threadIdx.x;
  const int wave = tid >> 6, lane = tid & 63;
  const int wm = wave >> 1, wn = wave & 1;

  // triangular decode: block -> (rt, ct), rt <= ct
  int rem = blockIdx.x, rt = 0;
  while (rem >= NT - rt) { rem -= NT - rt; ++rt; }
  const int ct = rt + rem;
  const int row0 = rt * 128, col0 = ct * 128;
  const bool isdiag = (rt == ct);

  if (isdiag) {
    // ---- prep tile rt: convert rows [row0,row0+128) to bf16, fp32 norms,
    //      init posk/negk for these rows, publish flag ----
    const int prow = row0 + (tid >> 1);
    const int c0 = (tid & 1) * 128;
    float s = 0.f;
    #pragma unroll 8
    for (int i = 0; i < 32; ++i) {
      const float4 v = *(const float4*)&F[prow * DIM + c0 + i * 4];
      s = fmaf(v.x, v.x, fmaf(v.y, v.y, fmaf(v.z, v.z, fmaf(v.w, v.w, s))));
      ushort4 o;
      o.x = f2b(v.x); o.y = f2b(v.y); o.z = f2b(v.z); o.w = f2b(v.w);
      *(ushort4*)&Fb[prow * DIM + c0 + i * 4] = o;
    }
    s += __shfl_xor(s, 1);                 // combine the two half-rows
    if ((tid & 1) == 0) nrm[prow] = s;
    if (tid < 128) {
      posk[row0 + tid] = enc_f(-1e30f);
      negk[row0 + tid] = enc_f(1e30f);
    }
    if (rt == 0 && tid == 0)
      __hip_atomic_store(ctr, 0u, __ATOMIC_RELAXED, __HIP_MEMORY_SCOPE_AGENT);
    __syncthreads();   // all threads' stores drained (vmcnt0 before barrier)
    if (tid == 0) {
      __threadfence();  // L2 writeback: make plain stores device-visible
      __hip_atomic_store(&flags[rt], READYF, __ATOMIC_RELEASE,
                         __HIP_MEMORY_SCOPE_AGENT);
      if (rt != 0) {    // order our later ctr increment after ctr=0 init
        while (__hip_atomic_load(&flags[0], __ATOMIC_ACQUIRE,
                                 __HIP_MEMORY_SCOPE_AGENT) != READYF)
          __builtin_amdgcn_s_sleep(2);
      }
    }
    __syncthreads();
  } else {
    // ---- wait for both source tiles (and tile 0 for ctr-init ordering) ----
    if (tid == 0) {
      while (__hip_atomic_load(&flags[rt], __ATOMIC_ACQUIRE,
                               __HIP_MEMORY_SCOPE_AGENT) != READYF)
        __builtin_amdgcn_s_sleep(2);
      while (__hip_atomic_load(&flags[ct], __ATOMIC_ACQUIRE,
                               __HIP_MEMORY_SCOPE_AGENT) != READYF)
        __builtin_amdgcn_s_sleep(2);
      while (__hip_atomic_load(&flags[0], __ATOMIC_ACQUIRE,
                               __HIP_MEMORY_SCOPE_AGENT) != READYF)
        __builtin_amdgcn_s_sleep(2);
      __threadfence();
    }
    __syncthreads();
  }

  if (tid < 128) { labi[tid] = lab[row0 + tid]; nrmi[tid] = nrm[row0 + tid]; }
  else { int t = tid - 128; labj[t] = lab[col0 + t]; nrmj[t] = nrm[col0 + t]; }

  f32x4 acc[4][4];
  #pragma unroll
  for (int m = 0; m < 4; ++m)
    #pragma unroll
    for (int n = 0; n < 4; ++n) acc[m][n] = (f32x4){0.f, 0.f, 0.f, 0.f};

  const int lrow = lane >> 2;        // row within a 16-row staging chunk
  const int lcol = (lane & 3) * 8;   // k offset (ushorts) within the chunk

  // prologue: stage kk=0 into buffer 0
  #pragma unroll
  for (int s = 0; s < 2; ++s) {
    const int rbase = s * 64 + wave * 16;
    gload_lds16(&Fb[(row0 + rbase + lrow) * DIM + lcol], &As[0][rbase * 32]);
    gload_lds16(&Fb[(col0 + rbase + lrow) * DIM + lcol], &Bs[0][rbase * 32]);
  }
  __syncthreads();   // compiler emits vmcnt(0) drain before barrier

  for (int kk = 0; kk < 8; ++kk) {
    const int cur = kk & 1;
    // issue next-tile staging BEFORE compute (overlaps with MFMA below)
    if (kk < 7) {
      const int nxt = cur ^ 1;
      #pragma unroll
      for (int s = 0; s < 2; ++s) {
        const int rbase = s * 64 + wave * 16;
        gload_lds16(&Fb[(row0 + rbase + lrow) * DIM + (kk + 1) * 32 + lcol], &As[nxt][rbase * 32]);
        gload_lds16(&Fb[(col0 + rbase + lrow) * DIM + (kk + 1) * 32 + lcol], &Bs[nxt][rbase * 32]);
      }
    }
    bf16x8 a[4], b[4];
    #pragma unroll
    for (int m = 0; m < 4; ++m)
      a[m] = *(const bf16x8*)&As[cur][(wm * 64 + m * 16 + (lane & 15)) * 32 + (lane >> 4) * 8];
    #pragma unroll
    for (int n = 0; n < 4; ++n)
      b[n] = *(const bf16x8*)&Bs[cur][(wn * 64 + n * 16 + (lane & 15)) * 32 + (lane >> 4) * 8];
    #pragma unroll
    for (int m = 0; m < 4; ++m)
      #pragma unroll
      for (int n = 0; n < 4; ++n)
        acc[m][n] = __builtin_amdgcn_mfma_f32_16x16x32_bf16(a[m], b[n], acc[m][n], 0, 0, 0);
    __syncthreads();   // vmcnt(0): next buffer staged; barrier for LDS reuse
  }

  // ---- fused two-sided mining epilogue ----
  // C/D layout: col = lane&15, row = (lane>>4)*4 + reg_idx  [m89/m91]
  const int h = lane >> 4, ccol = lane & 15;
  float posr[4][4], negr[4][4];   // row-side, per (m, j)
  float posc[4], negc[4];         // col-side, per n
  #pragma unroll
  for (int m = 0; m < 4; ++m)
    #pragma unroll
    for (int j = 0; j < 4; ++j) { posr[m][j] = -1e30f; negr[m][j] = 1e30f; }
  #pragma unroll
  for (int n = 0; n < 4; ++n) { posc[n] = -1e30f; negc[n] = 1e30f; }

  #pragma unroll
  for (int m = 0; m < 4; ++m) {
    #pragma unroll
    for (int n = 0; n < 4; ++n) {
      const int cl = wn * 64 + n * 16 + ccol;
      const float nj = nrmj[cl];
      const int lj = labj[cl];
      #pragma unroll
      for (int j = 0; j < 4; ++j) {
        const int rl = wm * 64 + m * 16 + h * 4 + j;
        const float sq = nrmi[rl] + nj - 2.f * acc[m][n][j];
        const bool same = (labi[rl] == lj);
        const bool self = isdiag && (rl == cl);
        if (same) {
          if (!self) {
            posr[m][j] = fmaxf(posr[m][j], sq);
            posc[n] = fmaxf(posc[n], sq);
          }
        } else {
          negr[m][j] = fminf(negr[m][j], sq);
          negc[n] = fminf(negc[n], sq);
        }
      }
    }
  }

  // row-side: reduce across the 16 col-lanes of each h-group
  #pragma unroll
  for (int m = 0; m < 4; ++m) {
    #pragma unroll
    for (int j = 0; j < 4; ++j) {
      float p = posr[m][j], q = negr[m][j];
      #pragma unroll
      for (int mask = 1; mask <= 8; mask <<= 1) {
        p = fmaxf(p, __shfl_xor(p, mask));
        q = fminf(q, __shfl_xor(q, mask));
      }
      if (ccol == 0) {
        const int rl = wm * 64 + m * 16 + h * 4 + j;
        redp[wn][rl] = p; redn[wn][rl] = q;
      }
    }
  }
  // col-side: reduce across the 4 h-groups (lane bits 4-5)
  #pragma unroll
  for (int n = 0; n < 4; ++n) {
    float p = posc[n], q = negc[n];
    #pragma unroll
    for (int mask = 16; mask <= 32; mask <<= 1) {
      p = fmaxf(p, __shfl_xor(p, mask));
      q = fminf(q, __shfl_xor(q, mask));
    }
    if (lane < 16) {
      redpc[wm][wn * 64 + n * 16 + lane] = p;
      rednc[wm][wn * 64 + n * 16 + lane] = q;
    }
  }
  __syncthreads();

  if (tid < 128) {
    // row-side result for row (row0+tid)
    const float p = fmaxf(redp[0][tid], redp[1][tid]);
    const float q = fminf(redn[0][tid], redn[1][tid]);
    atomicMax(&posk[row0 + tid], enc_f(p));
    atomicMin(&negk[row0 + tid], enc_f(q));
    if (!isdiag) {
      // col-side result for row (col0+tid)
      const float pc = fmaxf(redpc[0][tid], redpc[1][tid]);
      const float qc = fminf(rednc[0][tid], rednc[1][tid]);
      atomicMax(&posk[col0 + tid], enc_f(pc));
      atomicMin(&negk[col0 + tid], enc_f(qc));
    }
  }
  __syncthreads();   // all this block's atomics issued & complete

  if (tid == 0) {
    __threadfence();   // release: publish our atomics (they're at LLC already)
    is_last = (__hip_atomic_fetch_add(ctr, 1u, __ATOMIC_ACQ_REL,
                                      __HIP_MEMORY_SCOPE_AGENT) == NBLK - 1);
  }
  __syncthreads();
  if (!is_last) return;

  // ---- last block: mean loss. posk/negk were only ever touched by
  // device-scope atomics (LLC coherence point) -> no XCD L2 holds copies ->
  // plain vectorized loads are coherent here. ----
  __threadfence();
  float sum = 0.f, cntf = 0.f;
  #pragma unroll
  for (int it = 0; it < NROWS / (256 * 4); ++it) {
    const int i4 = (it * 256 + tid) * 4;
    const uint4 p4 = *(const uint4*)&posk[i4];
    const uint4 n4 = *(const uint4*)&negk[i4];
    const unsigned pv[4] = {p4.x, p4.y, p4.z, p4.w};
    const unsigned nv[4] = {n4.x, n4.y, n4.z, n4.w};
    #pragma unroll
    for (int e = 0; e < 4; ++e) {
      const float ps = dec_f(pv[e]);
      const float ns = dec_f(nv[e]);
      if ((ps > -1e29f) && (ns < 1e29f)) {
        const float hp = sqrtf(fmaxf(ps, 1e-12f));
        const float hn = sqrtf(fmaxf(ns, 1e-12f));
        sum += fmaxf(hp - hn + MARGINF, 0.f);
        cntf += 1.f;
      }
    }
  }
  #pragma unroll
  for (int off = 32; off; off >>= 1) {
    sum += __shfl_down(sum, off);
    cntf += __shfl_down(cntf, off);
  }
  if (lane == 0) { redp[0][wave] = sum; redn[0][wave] = cntf; }
  __syncthreads();
  if (tid == 0) {
    const float S = redp[0][0] + redp[0][1] + redp[0][2] + redp[0][3];
    const float C = redn[0][0] + redn[0][1] + redn[0][2] + redn[0][3];
    out[0] = (C > 0.f) ? (S / C) : 0.f;
  }
}

extern "C" void kernel_launch(void* const* d_in, const int* in_sizes, int n_in,
                              void* d_out, int out_size, void* d_ws, size_t ws_size,
                              hipStream_t stream) {
  const float* F = (const float*)d_in[0];
  const int* lab = (const int*)d_in[1];
  float* out = (float*)d_out;

  unsigned* posk = (unsigned*)d_ws;                 // [4096] 16KB
  unsigned* negk = posk + NROWS;                    // [4096] 16KB
  float* nrm = (float*)(negk + NROWS);              // [4096] 16KB
  unsigned* flags = (unsigned*)(nrm + NROWS);       // [32]   128B
  unsigned* ctr = flags + 32;                       // [4]    16B
  ushort_t* Fb = (ushort_t*)(ctr + 4);              // [4096*256] bf16, 16B-aligned

  k_all<<<NBLK, 256, 0, stream>>>(F, lab, Fb, nrm, posk, negk, flags, ctr, out);
}

// Round 11
// 78.683 us; speedup vs baseline: 2.2952x; 2.2952x over previous
//
#include <hip/hip_runtime.h>

typedef unsigned short ushort_t;
typedef __attribute__((ext_vector_type(8))) short bf16x8;
typedef __attribute__((ext_vector_type(4))) float f32x4;

#define NROWS 4096
#define DIM   256
#define NT    32                    // 128-row tiles
#define NBLK  (NT * (NT + 1) / 2)   // 528 triangular tiles
#define MARGINF 0.3f

// ---- order-preserving float<->uint encoding for atomic max/min ----
__device__ __forceinline__ unsigned enc_f(float f) {
  unsigned u = __float_as_uint(f);
  return (u & 0x80000000u) ? ~u : (u | 0x80000000u);
}
__device__ __forceinline__ float dec_f(unsigned k) {
  unsigned u = (k & 0x80000000u) ? (k ^ 0x80000000u) : ~k;
  return __uint_as_float(u);
}

__device__ __forceinline__ ushort_t f2b(float f) {  // fp32 -> bf16 bits, RNE
  unsigned u = __float_as_uint(f);
  u += 0x7fffu + ((u >> 16) & 1u);
  return (ushort_t)(u >> 16);
}

// Fragment-major bf16 layout: idx(row,k) = (row>>4)*4096 + (k>>3)*128
//                                        + (row&15)*8 + (k&7)
// With this, an MFMA 16x16x32 a/b fragment load for lane (h=lane>>4, r=lane&15)
// at 16-row group g, K-step kk is Fb2[g*4096 + kk*512 + h*128 + r*8] --
// 64 lanes x 16B = 1KB CONTIGUOUS (perfectly coalesced, no LDS needed).

// Fused: fp32->bf16 fragment-major convert + sq-norms + posk/negk init.
__global__ void k_prep(const float* __restrict__ F, ushort_t* __restrict__ Fb2,
                       float* __restrict__ nrm, unsigned* __restrict__ posk,
                       unsigned* __restrict__ negk) {
  const int tid = threadIdx.x;
  const int wave = tid >> 6, lane = tid & 63;
  const int row = blockIdx.x * 4 + wave;

  const float4 v = *(const float4*)&F[row * DIM + lane * 4];
  float s = fmaf(v.x, v.x, fmaf(v.y, v.y, fmaf(v.z, v.z, v.w * v.w)));
  #pragma unroll
  for (int off = 32; off; off >>= 1) s += __shfl_down(s, off);
  if (lane == 0) nrm[row] = s;

  ushort4 o;
  o.x = f2b(v.x); o.y = f2b(v.y); o.z = f2b(v.z); o.w = f2b(v.w);
  const int k0 = lane * 4;
  const unsigned idx = (unsigned)(row >> 4) * 4096u + (unsigned)(k0 >> 3) * 128u
                     + (unsigned)(row & 15) * 8u + (unsigned)(k0 & 7);
  *(ushort4*)&Fb2[idx] = o;

  const int gid = blockIdx.x * 256 + tid;
  if (gid < NROWS) { posk[gid] = enc_f(-1e30f); negk[gid] = enc_f(1e30f); }
}

// Upper-triangle Gram tiles (128x128, bf16 MFMA) with DIRECT register
// fragment loads from L2 (no LDS tiles, no K-loop barriers), fused two-sided
// batch-hard mining, atomic per-row finalize.
__global__ __launch_bounds__(256, 3) void k_gram(
    const ushort_t* __restrict__ Fb2, const int* __restrict__ lab,
    const float* __restrict__ nrm,
    unsigned* __restrict__ posk, unsigned* __restrict__ negk) {
  __shared__ int labi[128], labj[128];
  __shared__ float nrmi[128], nrmj[128];
  __shared__ float redp[2][128], redn[2][128];       // row-side, by wn
  __shared__ float redpc[2][128], rednc[2][128];     // col-side, by wm

  const int tid = threadIdx.x;
  const int wave = tid >> 6, lane = tid & 63;
  const int wm = wave >> 1, wn = wave & 1;

  // triangular decode: block -> (rt, ct), rt <= ct
  int rem = blockIdx.x, rt = 0;
  while (rem >= NT - rt) { rem -= NT - rt; ++rt; }
  const int ct = rt + rem;
  const int row0 = rt * 128, col0 = ct * 128;
  const bool isdiag = (rt == ct);

  if (tid < 128) { labi[tid] = lab[row0 + tid]; nrmi[tid] = nrm[row0 + tid]; }
  else { int t = tid - 128; labj[t] = lab[col0 + t]; nrmj[t] = nrm[col0 + t]; }
  __syncthreads();

  const int h = lane >> 4, r = lane & 15;
  // fragment base addresses (elements) in fragment-major Fb2
  const unsigned fbase = (unsigned)h * 128u + (unsigned)r * 8u;
  const unsigned abase = (unsigned)(rt * 8 + wm * 4) * 4096u + fbase;
  const unsigned bbase = (unsigned)(ct * 8 + wn * 4) * 4096u + fbase;

  f32x4 acc[4][4];
  #pragma unroll
  for (int m = 0; m < 4; ++m)
    #pragma unroll
    for (int n = 0; n < 4; ++n) acc[m][n] = (f32x4){0.f, 0.f, 0.f, 0.f};

  // K-loop: pure register dataflow -- 8 coalesced 1KB loads + 16 MFMA per kk,
  // no barriers, no LDS. L2-resident (Fb2 = 2MB <= 4MB per-XCD L2).
  #pragma unroll
  for (int kk = 0; kk < 8; ++kk) {
    bf16x8 a[4], b[4];
    #pragma unroll
    for (int m = 0; m < 4; ++m)
      a[m] = *(const bf16x8*)&Fb2[abase + (unsigned)m * 4096u + (unsigned)kk * 512u];
    #pragma unroll
    for (int n = 0; n < 4; ++n)
      b[n] = *(const bf16x8*)&Fb2[bbase + (unsigned)n * 4096u + (unsigned)kk * 512u];
    #pragma unroll
    for (int m = 0; m < 4; ++m)
      #pragma unroll
      for (int n = 0; n < 4; ++n)
        acc[m][n] = __builtin_amdgcn_mfma_f32_16x16x32_bf16(a[m], b[n], acc[m][n], 0, 0, 0);
  }

  // ---- fused two-sided mining epilogue ----
  // C/D layout: col = lane&15, row = (lane>>4)*4 + reg_idx  [m89/m91]
  const int ccol = r;
  float posr[4][4], negr[4][4];   // row-side, per (m, j)
  float posc[4], negc[4];         // col-side, per n
  #pragma unroll
  for (int m = 0; m < 4; ++m)
    #pragma unroll
    for (int j = 0; j < 4; ++j) { posr[m][j] = -1e30f; negr[m][j] = 1e30f; }
  #pragma unroll
  for (int n = 0; n < 4; ++n) { posc[n] = -1e30f; negc[n] = 1e30f; }

  #pragma unroll
  for (int m = 0; m < 4; ++m) {
    #pragma unroll
    for (int n = 0; n < 4; ++n) {
      const int cl = wn * 64 + n * 16 + ccol;
      const float nj = nrmj[cl];
      const int lj = labj[cl];
      #pragma unroll
      for (int j = 0; j < 4; ++j) {
        const int rl = wm * 64 + m * 16 + h * 4 + j;
        const float sq = nrmi[rl] + nj - 2.f * acc[m][n][j];
        const bool same = (labi[rl] == lj);
        const bool self = isdiag && (rl == cl);
        if (same) {
          if (!self) {
            posr[m][j] = fmaxf(posr[m][j], sq);
            posc[n] = fmaxf(posc[n], sq);
          }
        } else {
          negr[m][j] = fminf(negr[m][j], sq);
          negc[n] = fminf(negc[n], sq);
        }
      }
    }
  }

  // row-side: reduce across the 16 col-lanes of each h-group
  #pragma unroll
  for (int m = 0; m < 4; ++m) {
    #pragma unroll
    for (int j = 0; j < 4; ++j) {
      float p = posr[m][j], q = negr[m][j];
      #pragma unroll
      for (int mask = 1; mask <= 8; mask <<= 1) {
        p = fmaxf(p, __shfl_xor(p, mask));
        q = fminf(q, __shfl_xor(q, mask));
      }
      if (ccol == 0) {
        const int rl = wm * 64 + m * 16 + h * 4 + j;
        redp[wn][rl] = p; redn[wn][rl] = q;
      }
    }
  }
  // col-side: reduce across the 4 h-groups (lane bits 4-5)
  #pragma unroll
  for (int n = 0; n < 4; ++n) {
    float p = posc[n], q = negc[n];
    #pragma unroll
    for (int mask = 16; mask <= 32; mask <<= 1) {
      p = fmaxf(p, __shfl_xor(p, mask));
      q = fminf(q, __shfl_xor(q, mask));
    }
    if (lane < 16) {
      redpc[wm][wn * 64 + n * 16 + lane] = p;
      rednc[wm][wn * 64 + n * 16 + lane] = q;
    }
  }
  __syncthreads();

  if (tid < 128) {
    // row-side result for row (row0+tid)
    const float p = fmaxf(redp[0][tid], redp[1][tid]);
    const float q = fminf(redn[0][tid], redn[1][tid]);
    atomicMax(&posk[row0 + tid], enc_f(p));
    atomicMin(&negk[row0 + tid], enc_f(q));
    if (!isdiag) {
      // col-side result for row (col0+tid)
      const float pc = fmaxf(redpc[0][tid], redpc[1][tid]);
      const float qc = fminf(rednc[0][tid], rednc[1][tid]);
      atomicMax(&posk[col0 + tid], enc_f(pc));
      atomicMin(&negk[col0 + tid], enc_f(qc));
    }
  }
}

__global__ void k_final(const unsigned* __restrict__ posk,
                        const unsigned* __restrict__ negk,
                        float* __restrict__ out) {
  int t = threadIdx.x;  // 1024 threads
  float sum = 0.f;
  int cnt = 0;
  for (int i = t; i < NROWS; i += 1024) {
    float ps = dec_f(posk[i]);
    float ns = dec_f(negk[i]);
    if ((ps > -1e29f) && (ns < 1e29f)) {
      float hp = sqrtf(fmaxf(ps, 1e-12f));
      float hn = sqrtf(fmaxf(ns, 1e-12f));
      sum += fmaxf(hp - hn + MARGINF, 0.f);
      cnt += 1;
    }
  }
  #pragma unroll
  for (int off = 32; off; off >>= 1) {
    sum += __shfl_down(sum, off);
    cnt += __shfl_down(cnt, off);
  }
  __shared__ float wsum[16];
  __shared__ int wcnt[16];
  int w = t >> 6;
  if ((t & 63) == 0) { wsum[w] = sum; wcnt[w] = cnt; }
  __syncthreads();
  if (t == 0) {
    float S = 0.f; int C = 0;
    #pragma unroll
    for (int i = 0; i < 16; ++i) { S += wsum[i]; C += wcnt[i]; }
    out[0] = (C > 0) ? (S / (float)C) : 0.f;
  }
}

extern "C" void kernel_launch(void* const* d_in, const int* in_sizes, int n_in,
                              void* d_out, int out_size, void* d_ws, size_t ws_size,
                              hipStream_t stream) {
  const float* F = (const float*)d_in[0];
  const int* lab = (const int*)d_in[1];
  float* out = (float*)d_out;

  unsigned* posk = (unsigned*)d_ws;                 // [4096] 16KB
  unsigned* negk = posk + NROWS;                    // [4096] 16KB
  float* nrm = (float*)(negk + NROWS);              // [4096] 16KB
  ushort_t* Fb2 = (ushort_t*)(nrm + NROWS);         // [4096*256] bf16 frag-major

  k_prep<<<NROWS / 4, 256, 0, stream>>>(F, Fb2, nrm, posk, negk);
  k_gram<<<NBLK, 256, 0, stream>>>(Fb2, lab, nrm, posk, negk);
  k_final<<<1, 1024, 0, stream>>>(posk, negk, out);
}